// Round 1
// baseline (279.438 us; speedup 1.0000x reference)
//
#include <hip/hip_runtime.h>

#define BH_ 16
#define S_ 2048
#define D_ 128
#define QB_ 64
#define KB_ 64

typedef __attribute__((ext_vector_type(4))) float f32x4;
typedef __attribute__((ext_vector_type(8))) short bf16x8;

__device__ __forceinline__ unsigned short f2bf(float x) {
  union { float f; unsigned int u; } v; v.f = x;
  unsigned int r = v.u + 0x7fffu + ((v.u >> 16) & 1u);  // RNE
  return (unsigned short)(r >> 16);
}
__device__ __forceinline__ float bf2f(unsigned short b) {
  union { float f; unsigned int u; } v; v.u = ((unsigned int)b) << 16;
  return v.f;
}

// Block = (bh, 64 q-rows). 4 waves, wave w owns q-rows [16w,16w+16).
// Pass 1: row sums of exp(QK^T) (causal). Pass 2: recompute scores
// (bit-identical), write attn = exp(s)/l, accumulate O = P V, then out = O*q.
// Scores use bf16 hi/lo split (hh+hl+lh) for ~fp32 accuracy.
__global__ __launch_bounds__(256, 2)
void sdpa_kernel(const float* __restrict__ Q, const float* __restrict__ K,
                 const float* __restrict__ V, float* __restrict__ out,
                 float* __restrict__ attn)
{
  // K tile [64 k-rows][128 d] bf16 hi/lo, XOR-swizzled (G4): 16 KB each
  __shared__ unsigned short khi[KB_ * D_];
  __shared__ unsigned short klo[KB_ * D_];
  // V^T tile [128 d][64 k] bf16, XOR-swizzled: 16 KB
  __shared__ unsigned short vts[D_ * KB_];
  // per-wave P tile [16 q][64 k] bf16, XOR-swizzled: 2 KB x 4
  __shared__ unsigned short pls[4][16 * KB_];

  const int tid  = threadIdx.x;
  const int w    = tid >> 6;
  const int lane = tid & 63;
  const int g    = lane >> 4;   // 4-group (k-chunk selector in frags)
  const int c    = lane & 15;   // row/col within 16

  const int bh = blockIdx.y;
  const int qb = (int)gridDim.x - 1 - (int)blockIdx.x;  // heavy blocks first
  const int q0 = qb * QB_;

  const float* Qb = Q + (size_t)bh * S_ * D_;
  const float* Kb = K + (size_t)bh * S_ * D_;
  const float* Vb = V + (size_t)bh * S_ * D_;
  float* outb  = out  + (size_t)bh * S_ * D_;
  float* attnb = attn + (size_t)bh * S_ * S_;

  // ---- zero-fill fully masked columns [q0+64, S) for this block's rows ----
  {
    const int colstart = q0 + QB_;
    for (int r = 0; r < QB_; ++r) {
      float* rowp = attnb + (size_t)(q0 + r) * S_;
      for (int col = colstart + tid * 4; col < S_; col += 1024) {
        *(float4*)(rowp + col) = make_float4(0.f, 0.f, 0.f, 0.f);
      }
    }
  }

  // ---- load Q fragments, split into bf16 hi/lo (A-frag: row=c, k=8g+i+32ch) ----
  bf16x8 qhi[4], qlo[4];
  {
    const float* qrow = Qb + (size_t)(q0 + w * 16 + c) * D_;
#pragma unroll
    for (int ch = 0; ch < 4; ++ch) {
      const float* src = qrow + ch * 32 + g * 8;
      float4 a = *(const float4*)src;
      float4 b = *(const float4*)(src + 4);
      float xs[8] = {a.x, a.y, a.z, a.w, b.x, b.y, b.z, b.w};
#pragma unroll
      for (int i = 0; i < 8; ++i) {
        unsigned short h = f2bf(xs[i]);
        unsigned short l = f2bf(xs[i] - bf2f(h));
        qhi[ch][i] = (short)h;
        qlo[ch][i] = (short)l;
      }
    }
  }

  // stage K block kb into khi/klo (coalesced read, swizzled b64 writes)
  auto stageK = [&](int kb) {
#pragma unroll
    for (int rr = 0; rr < 8; ++rr) {
      int flat = tid * 4 + rr * 1024;      // element in 64x128 tile
      int kj = flat >> 7, d0 = flat & 127;
      const float* src = Kb + (size_t)(kb * KB_ + kj) * D_ + d0;
      float4 f = *(const float4*)src;
      unsigned short h0 = f2bf(f.x), h1 = f2bf(f.y), h2 = f2bf(f.z), h3 = f2bf(f.w);
      unsigned short l0 = f2bf(f.x - bf2f(h0)), l1 = f2bf(f.y - bf2f(h1));
      unsigned short l2 = f2bf(f.z - bf2f(h2)), l3 = f2bf(f.w - bf2f(h3));
      int off = kj * 256 + ((d0 * 2) ^ ((kj & 7) << 4));
      *(uint2*)((char*)khi + off) =
          make_uint2((unsigned)h0 | ((unsigned)h1 << 16), (unsigned)h2 | ((unsigned)h3 << 16));
      *(uint2*)((char*)klo + off) =
          make_uint2((unsigned)l0 | ((unsigned)l1 << 16), (unsigned)l2 | ((unsigned)l3 << 16));
    }
  };

  // S tile (16q x 64k per wave) via 3-way split MFMA; identical in both passes
  const f32x4 zero4 = {0.f, 0.f, 0.f, 0.f};
  auto computeS = [&](f32x4* acc) {
#pragma unroll
    for (int t = 0; t < 4; ++t) {
      acc[t] = zero4;
      int row = t * 16 + c;            // K row (B-frag col = c)
      int rbase = row * 256;
      int sw = (row & 7) << 4;
#pragma unroll
      for (int c2 = 0; c2 < 4; ++c2) {
        int off = rbase + ((c2 * 64 + g * 16) ^ sw);
        bf16x8 kh_ = *(const bf16x8*)((const char*)khi + off);
        bf16x8 kl_ = *(const bf16x8*)((const char*)klo + off);
        acc[t] = __builtin_amdgcn_mfma_f32_16x16x32_bf16(qhi[c2], kh_, acc[t], 0, 0, 0);
        acc[t] = __builtin_amdgcn_mfma_f32_16x16x32_bf16(qhi[c2], kl_, acc[t], 0, 0, 0);
        acc[t] = __builtin_amdgcn_mfma_f32_16x16x32_bf16(qlo[c2], kh_, acc[t], 0, 0, 0);
      }
    }
  };

  // ---- pass 1: row sums l = sum_k exp(s) over causal k ----
  float rsum[4] = {0.f, 0.f, 0.f, 0.f};
  for (int kb = 0; kb <= qb; ++kb) {
    __syncthreads();
    stageK(kb);
    __syncthreads();
    f32x4 acc[4];
    computeS(acc);
#pragma unroll
    for (int r2 = 0; r2 < 4; ++r2) {
      int qg = q0 + w * 16 + g * 4 + r2;   // C/D row = 4g+r2
      float s0 = 0.f;
#pragma unroll
      for (int t = 0; t < 4; ++t) {
        int kg = kb * KB_ + t * 16 + c;    // C/D col = c
        float e = (kg <= qg) ? __expf(acc[t][r2]) : 0.f;
        s0 += e;
      }
#pragma unroll
      for (int m = 1; m <= 8; m <<= 1) s0 += __shfl_xor(s0, m, 64);
      rsum[r2] += s0;
    }
  }
  float invl[4];
#pragma unroll
  for (int r2 = 0; r2 < 4; ++r2) invl[r2] = 1.0f / rsum[r2];

  // ---- pass 2: recompute, write attn, accumulate O = P V ----
  f32x4 oacc[8];
#pragma unroll
  for (int dt = 0; dt < 8; ++dt) oacc[dt] = zero4;

  for (int kb = 0; kb <= qb; ++kb) {
    __syncthreads();
    stageK(kb);
    // stage V^T: lane reads V[k=lane][d0..d0+4] (strided 16B granules, L2-hot),
    // writes rows d of vts -- row is wave-uniform per write => conflict-free
#pragma unroll
    for (int rr = 0; rr < 8; ++rr) {
      int d0 = 4 * (w + 4 * rr);
      const float* src = Vb + (size_t)(kb * KB_ + lane) * D_ + d0;
      float4 f = *(const float4*)src;
      float xs[4] = {f.x, f.y, f.z, f.w};
#pragma unroll
      for (int i = 0; i < 4; ++i) {
        int d = d0 + i;
        int off = d * 128 + ((lane * 2) ^ ((d & 7) << 4));
        *(unsigned short*)((char*)vts + off) = f2bf(xs[i]);
      }
    }
    __syncthreads();

    f32x4 acc[4];
    computeS(acc);

    // p = exp(s) / l ; write f32 attn + bf16 P into per-wave LDS
#pragma unroll
    for (int r2 = 0; r2 < 4; ++r2) {
      int qrow = g * 4 + r2;
      int qg = q0 + w * 16 + qrow;
#pragma unroll
      for (int t = 0; t < 4; ++t) {
        int kc = t * 16 + c;
        int kg = kb * KB_ + kc;
        float p = (kg <= qg) ? __expf(acc[t][r2]) * invl[r2] : 0.f;
        attnb[(size_t)qg * S_ + kg] = p;
        int off = qrow * 128 + ((kc * 2) ^ ((qrow & 7) << 4));
        *(unsigned short*)((char*)pls[w] + off) = f2bf(p);
      }
    }
    __syncthreads();

    // PV: A-frag = P (row=c, k=8g+i+32ks), B-frag = V^T rows (col=c in d-tile)
    bf16x8 pa[2];
#pragma unroll
    for (int ks = 0; ks < 2; ++ks) {
      int off = c * 128 + ((ks * 64 + g * 16) ^ ((c & 7) << 4));
      pa[ks] = *(const bf16x8*)((const char*)pls[w] + off);
    }
#pragma unroll
    for (int dt = 0; dt < 8; ++dt) {
      int d = dt * 16 + c;
      int rbase = d * 128;
      int sw = (d & 7) << 4;
#pragma unroll
      for (int ks = 0; ks < 2; ++ks) {
        int off = rbase + ((ks * 64 + g * 16) ^ sw);
        bf16x8 vf = *(const bf16x8*)((const char*)vts + off);
        oacc[dt] = __builtin_amdgcn_mfma_f32_16x16x32_bf16(pa[ks], vf, oacc[dt], 0, 0, 0);
      }
    }
  }

  // ---- epilogue: out = O * q (faithful quirk) ----
#pragma unroll
  for (int dt = 0; dt < 8; ++dt) {
#pragma unroll
    for (int r2 = 0; r2 < 4; ++r2) {
      int qg = q0 + w * 16 + g * 4 + r2;
      int d = dt * 16 + c;
      float qv = Qb[(size_t)qg * D_ + d];
      outb[(size_t)qg * D_ + d] = oacc[dt][r2] * qv;
    }
  }
}

extern "C" void kernel_launch(void* const* d_in, const int* in_sizes, int n_in,
                              void* d_out, int out_size, void* d_ws, size_t ws_size,
                              hipStream_t stream) {
  const float* q = (const float*)d_in[0];
  const float* k = (const float*)d_in[1];
  const float* v = (const float*)d_in[2];
  // d_in[3] = causal mask: fixed, recomputed on the fly.
  float* out  = (float*)d_out;
  float* attn = out + (size_t)BH_ * S_ * D_;
  dim3 grid(S_ / QB_, BH_);
  sdpa_kernel<<<grid, dim3(256), 0, stream>>>(q, k, v, out, attn);
}

// Round 3
// 175.921 us; speedup vs baseline: 1.5884x; 1.5884x over previous
//
#include <hip/hip_runtime.h>

#define BH_ 16
#define S_ 2048
#define D_ 128
#define QB_ 64
#define KB_ 64

typedef __attribute__((ext_vector_type(4))) float f32x4;
typedef __attribute__((ext_vector_type(8))) short bf16x8;
typedef unsigned short ushort_t;

__device__ __forceinline__ unsigned short f2bf(float x) {
  union { float f; unsigned int u; } v; v.f = x;
  unsigned int r = v.u + 0x7fffu + ((v.u >> 16) & 1u);  // RNE
  return (unsigned short)(r >> 16);
}
__device__ __forceinline__ float bf2f(unsigned short b) {
  union { float f; unsigned int u; } v; v.u = ((unsigned int)b) << 16;
  return v.f;
}
__device__ __forceinline__ void gload16(const void* g, void* l) {
  __builtin_amdgcn_global_load_lds(
      (const __attribute__((address_space(1))) unsigned int*)g,
      (__attribute__((address_space(3))) unsigned int*)l, 16, 0, 0);
}

// ---------- k0a: K (f32) -> Khi/Klo bf16, same [bh][s][d] layout ----------
__global__ __launch_bounds__(256) void convK(const float* __restrict__ K,
                                             ushort_t* __restrict__ hi,
                                             ushort_t* __restrict__ lo) {
  size_t i = (size_t)blockIdx.x * 256 + threadIdx.x;  // 8 floats per thread
  const float4* p = (const float4*)K + i * 2;
  float4 a = p[0], b = p[1];
  float xs[8] = {a.x, a.y, a.z, a.w, b.x, b.y, b.z, b.w};
  union { ushort_t u[8]; uint4 v; } H, L;
#pragma unroll
  for (int j = 0; j < 8; ++j) {
    unsigned short h = f2bf(xs[j]);
    H.u[j] = h;
    L.u[j] = f2bf(xs[j] - bf2f(h));
  }
  ((uint4*)hi)[i] = H.v;
  ((uint4*)lo)[i] = L.v;
}

// ---------- k0b: V (f32 [bh][s][d]) -> Vt bf16 [bh][d][s] ----------
__global__ __launch_bounds__(256) void transV(const float* __restrict__ V,
                                              ushort_t* __restrict__ Vt) {
  __shared__ ushort_t tile[64][136];
  const int tid = threadIdx.x;
  const int bh = blockIdx.y;
  const int s0 = blockIdx.x * 64;
  const float* Vb = V + ((size_t)bh * S_ + s0) * D_;
#pragma unroll
  for (int it = 0; it < 8; ++it) {
    int idx = it * 256 + tid;           // float4 index within 64x128 tile
    int fl = idx * 4;
    int s = fl >> 7, d = fl & 127;
    float4 f = *(const float4*)(Vb + (size_t)s * D_ + d);
    tile[s][d + 0] = f2bf(f.x);
    tile[s][d + 1] = f2bf(f.y);
    tile[s][d + 2] = f2bf(f.z);
    tile[s][d + 3] = f2bf(f.w);
  }
  __syncthreads();
  const int d = tid >> 1, half = tid & 1;
  union { ushort_t u[32]; uint4 v[4]; } T;
#pragma unroll
  for (int i = 0; i < 32; ++i) T.u[i] = tile[half * 32 + i][d];
  ushort_t* dst = Vt + (size_t)bh * D_ * S_ + (size_t)d * S_ + s0 + half * 32;
#pragma unroll
  for (int i = 0; i < 4; ++i) ((uint4*)dst)[i] = T.v[i];
}

// ---------- k1: single-pass attention (unnormalized attn out) ----------
// Block = (bh, q-tile pair {31-x, x}) => 33 k-tiles/block, perfectly balanced.
// K/V tiles double-buffered in LDS via global_load_lds from preconverted ws.
__global__ __launch_bounds__(256) void sdpa_main(
    const float* __restrict__ Q, const ushort_t* __restrict__ Khi,
    const ushort_t* __restrict__ Klo, const ushort_t* __restrict__ Vt,
    float* __restrict__ out, float* __restrict__ attn,
    float* __restrict__ rsumW) {
  __shared__ ushort_t khi[2][KB_ * D_];   // 16 KB each, XOR-swizzled content
  __shared__ ushort_t klo[2][KB_ * D_];
  __shared__ ushort_t vts[2][D_ * KB_];
  __shared__ ushort_t pls[4][16 * KB_];   // per-wave P tile

  const int tid  = threadIdx.x;
  const int w    = tid >> 6;
  const int lane = tid & 63;
  const int g    = lane >> 4;
  const int c    = lane & 15;

  const int bh  = blockIdx.y;
  const int qbA = 31 - (int)blockIdx.x;   // heavy tile
  const int qbB = (int)blockIdx.x;        // light tile
  const int nA  = qbA + 1;
  const int nTot = nA + qbB + 1;          // 33

  const float* Qb = Q + (size_t)bh * S_ * D_;
  const char* KhiB = (const char*)Khi + (size_t)bh * S_ * D_ * 2;
  const char* KloB = (const char*)Klo + (size_t)bh * S_ * D_ * 2;
  const char* VtB  = (const char*)Vt  + (size_t)bh * D_ * S_ * 2;
  float* outb  = out  + (size_t)bh * S_ * D_;
  float* attnb = attn + (size_t)bh * S_ * S_;

  // stage K/V tile kb into buffer bi (12 x global_load_lds per wave).
  // LDS dest is linear; source address carries the inverse XOR swizzle.
  auto stage = [&](int bi, int kb) {
    const char* hs = KhiB + (size_t)kb * (KB_ * D_ * 2);
    const char* ls = KloB + (size_t)kb * (KB_ * D_ * 2);
    const char* vs = VtB + (size_t)kb * (KB_ * 2);
#pragma unroll
    for (int i = 0; i < 4; ++i) {
      int ch = w * 4 + i;
      int db = ch * 1024 + lane * 16;
      {
        int r = db >> 8, cb = db & 255;
        int so = r * 256 + (cb ^ ((r & 7) << 4));
        gload16(hs + so, (char*)khi[bi] + ch * 1024);
        gload16(ls + so, (char*)klo[bi] + ch * 1024);
      }
      {
        int r = db >> 7, cb = db & 127;
        int so = r * (S_ * 2) + (cb ^ ((r & 7) << 4));
        gload16(vs + so, (char*)vts[bi] + ch * 1024);
      }
    }
  };

  // Q fragments (bf16 hi/lo) for current q-tile
  bf16x8 qhi[4], qlo[4];
  auto loadQ = [&](int qb) {
    const float* qrow = Qb + (size_t)(qb * QB_ + w * 16 + c) * D_;
#pragma unroll
    for (int ch = 0; ch < 4; ++ch) {
      const float* src = qrow + ch * 32 + g * 8;
      float4 a = *(const float4*)src;
      float4 b = *(const float4*)(src + 4);
      float xs[8] = {a.x, a.y, a.z, a.w, b.x, b.y, b.z, b.w};
#pragma unroll
      for (int i = 0; i < 8; ++i) {
        unsigned short h = f2bf(xs[i]);
        qhi[ch][i] = (short)h;
        qlo[ch][i] = (short)f2bf(xs[i] - bf2f(h));
      }
    }
  };

  const f32x4 zero4 = {0.f, 0.f, 0.f, 0.f};
  f32x4 oacc[8];
  float rs[4];
#pragma unroll
  for (int dt = 0; dt < 8; ++dt) oacc[dt] = zero4;
#pragma unroll
  for (int r2 = 0; r2 < 4; ++r2) rs[r2] = 0.f;

  // epilogue for a finished q-tile: reduce rsum, scale O, write out & rsum
  auto finishTile = [&](int qb) {
    const int q0 = qb * QB_;
    float inv[4];
#pragma unroll
    for (int r2 = 0; r2 < 4; ++r2) {
      float s0 = rs[r2];
#pragma unroll
      for (int m = 1; m <= 8; m <<= 1) s0 += __shfl_xor(s0, m, 64);
      inv[r2] = 1.0f / s0;
      if (c == 0)
        rsumW[(size_t)bh * S_ + q0 + w * 16 + g * 4 + r2] = s0;
    }
#pragma unroll
    for (int dt = 0; dt < 8; ++dt) {
#pragma unroll
      for (int r2 = 0; r2 < 4; ++r2) {
        int qg = q0 + w * 16 + g * 4 + r2;
        int d = dt * 16 + c;
        outb[(size_t)qg * D_ + d] = oacc[dt][r2] * inv[r2] * Qb[(size_t)qg * D_ + d];
      }
    }
#pragma unroll
    for (int dt = 0; dt < 8; ++dt) oacc[dt] = zero4;
#pragma unroll
    for (int r2 = 0; r2 < 4; ++r2) rs[r2] = 0.f;
  };

  loadQ(qbA);
  stage(0, 0);
  int cur = 0;

  for (int j = 0; j < nTot; ++j) {
    __syncthreads();  // drains vmcnt: buf[cur] staged; all waves past prev PV
    int nj = j + 1;
    if (nj < nTot) stage(cur ^ 1, (nj < nA) ? nj : nj - nA);
    if (j == nA) { finishTile(qbA); loadQ(qbB); }
    const int qb = (j < nA) ? qbA : qbB;
    const int q0 = qb * QB_;
    const int kb = (j < nA) ? j : j - nA;

    // ---- QK^T (3-way hi/lo split), 4 independent acc chains ----
    f32x4 acc[4];
#pragma unroll
    for (int t = 0; t < 4; ++t) acc[t] = zero4;
#pragma unroll
    for (int c2 = 0; c2 < 4; ++c2) {
      bf16x8 kh[4], kl[4];
#pragma unroll
      for (int t = 0; t < 4; ++t) {
        int row = t * 16 + c;
        int off = row * 256 + (((c2 * 64 + g * 16)) ^ ((row & 7) << 4));
        kh[t] = *(const bf16x8*)((const char*)khi[cur] + off);
        kl[t] = *(const bf16x8*)((const char*)klo[cur] + off);
      }
#pragma unroll
      for (int t = 0; t < 4; ++t)
        acc[t] = __builtin_amdgcn_mfma_f32_16x16x32_bf16(qhi[c2], kh[t], acc[t], 0, 0, 0);
#pragma unroll
      for (int t = 0; t < 4; ++t)
        acc[t] = __builtin_amdgcn_mfma_f32_16x16x32_bf16(qlo[c2], kh[t], acc[t], 0, 0, 0);
#pragma unroll
      for (int t = 0; t < 4; ++t)
        acc[t] = __builtin_amdgcn_mfma_f32_16x16x32_bf16(qhi[c2], kl[t], acc[t], 0, 0, 0);
    }

    // ---- exp (unnormalized), attn store, rsum accum, P -> LDS ----
#pragma unroll
    for (int r2 = 0; r2 < 4; ++r2) {
      int qrow = g * 4 + r2;
      int qg = q0 + w * 16 + qrow;
      float* arow = attnb + (size_t)qg * S_;
#pragma unroll
      for (int t = 0; t < 4; ++t) {
        int kc = t * 16 + c;
        int kg = kb * KB_ + kc;
        float e = (kg <= qg) ? __expf(acc[t][r2]) : 0.f;
        rs[r2] += e;
        arow[kg] = e;
        int off = qrow * 128 + ((kc * 2) ^ ((qrow & 7) << 4));
        *(ushort_t*)((char*)pls[w] + off) = f2bf(e);
      }
    }

    // ---- PV (own-wave LDS, lgkmcnt-ordered; no barrier needed) ----
    bf16x8 pa[2];
#pragma unroll
    for (int ks = 0; ks < 2; ++ks) {
      int off = c * 128 + ((ks * 64 + g * 16) ^ ((c & 7) << 4));
      pa[ks] = *(const bf16x8*)((const char*)pls[w] + off);
    }
#pragma unroll
    for (int ks = 0; ks < 2; ++ks) {
#pragma unroll
      for (int dt = 0; dt < 8; ++dt) {
        int d = dt * 16 + c;
        int off = d * 128 + ((ks * 64 + g * 16) ^ ((d & 7) << 4));
        bf16x8 vf = *(const bf16x8*)((const char*)vts[cur] + off);
        oacc[dt] = __builtin_amdgcn_mfma_f32_16x16x32_bf16(pa[ks], vf, oacc[dt], 0, 0, 0);
      }
    }
    cur ^= 1;
  }
  finishTile(qbB);
}

// ---------- k2: attn rows: scale lower-tri by 1/l, zero upper ----------
__global__ __launch_bounds__(256) void norm_attn(float* __restrict__ attn,
                                                 const float* __restrict__ rsumW) {
  const int tid = threadIdx.x;
  const int bh = blockIdx.y;
  const int rp = blockIdx.x;  // [0, S_/2): rows rp and S_-1-rp (balanced)
#pragma unroll
  for (int which = 0; which < 2; ++which) {
    const int q = which ? (S_ - 1 - rp) : rp;
    const float inv = 1.0f / rsumW[(size_t)bh * S_ + q];
    float* row = attn + ((size_t)bh * S_ + q) * S_;
    const int ncol = q + 1;
    for (int col = tid * 4; col < S_; col += 1024) {
      float4 x;
      if (col + 4 <= ncol) {
        x = *(const float4*)(row + col);
        x.x *= inv; x.y *= inv; x.z *= inv; x.w *= inv;
      } else if (col >= ncol) {
        x = make_float4(0.f, 0.f, 0.f, 0.f);
      } else {
        float t[4];
#pragma unroll
        for (int j = 0; j < 4; ++j) {
          int cc = col + j;
          t[j] = (cc < ncol) ? row[cc] * inv : 0.f;
        }
        x = make_float4(t[0], t[1], t[2], t[3]);
      }
      *(float4*)(row + col) = x;
    }
  }
}

// ---------- fallback (round-1 kernel, self-contained) ----------
__global__ __launch_bounds__(256, 2)
void sdpa_fallback(const float* __restrict__ Q, const float* __restrict__ K,
                   const float* __restrict__ V, float* __restrict__ out,
                   float* __restrict__ attn)
{
  __shared__ unsigned short khi[KB_ * D_];
  __shared__ unsigned short klo[KB_ * D_];
  __shared__ unsigned short vts[D_ * KB_];
  __shared__ unsigned short pls[4][16 * KB_];

  const int tid  = threadIdx.x;
  const int w    = tid >> 6;
  const int lane = tid & 63;
  const int g    = lane >> 4;
  const int c    = lane & 15;

  const int bh = blockIdx.y;
  const int qb = (int)gridDim.x - 1 - (int)blockIdx.x;
  const int q0 = qb * QB_;

  const float* Qb = Q + (size_t)bh * S_ * D_;
  const float* Kb = K + (size_t)bh * S_ * D_;
  const float* Vb = V + (size_t)bh * S_ * D_;
  float* outb  = out  + (size_t)bh * S_ * D_;
  float* attnb = attn + (size_t)bh * S_ * S_;

  {
    const int colstart = q0 + QB_;
    for (int r = 0; r < QB_; ++r) {
      float* rowp = attnb + (size_t)(q0 + r) * S_;
      for (int col = colstart + tid * 4; col < S_; col += 1024)
        *(float4*)(rowp + col) = make_float4(0.f, 0.f, 0.f, 0.f);
    }
  }

  bf16x8 qhi[4], qlo[4];
  {
    const float* qrow = Qb + (size_t)(q0 + w * 16 + c) * D_;
#pragma unroll
    for (int ch = 0; ch < 4; ++ch) {
      const float* src = qrow + ch * 32 + g * 8;
      float4 a = *(const float4*)src;
      float4 b = *(const float4*)(src + 4);
      float xs[8] = {a.x, a.y, a.z, a.w, b.x, b.y, b.z, b.w};
#pragma unroll
      for (int i = 0; i < 8; ++i) {
        unsigned short h = f2bf(xs[i]);
        unsigned short l = f2bf(xs[i] - bf2f(h));
        qhi[ch][i] = (short)h;
        qlo[ch][i] = (short)l;
      }
    }
  }

  auto stageK = [&](int kb) {
#pragma unroll
    for (int rr = 0; rr < 8; ++rr) {
      int flat = tid * 4 + rr * 1024;
      int kj = flat >> 7, d0 = flat & 127;
      const float* src = Kb + (size_t)(kb * KB_ + kj) * D_ + d0;
      float4 f = *(const float4*)src;
      unsigned short h0 = f2bf(f.x), h1 = f2bf(f.y), h2 = f2bf(f.z), h3 = f2bf(f.w);
      unsigned short l0 = f2bf(f.x - bf2f(h0)), l1 = f2bf(f.y - bf2f(h1));
      unsigned short l2 = f2bf(f.z - bf2f(h2)), l3 = f2bf(f.w - bf2f(h3));
      int off = kj * 256 + ((d0 * 2) ^ ((kj & 7) << 4));
      *(uint2*)((char*)khi + off) =
          make_uint2((unsigned)h0 | ((unsigned)h1 << 16), (unsigned)h2 | ((unsigned)h3 << 16));
      *(uint2*)((char*)klo + off) =
          make_uint2((unsigned)l0 | ((unsigned)l1 << 16), (unsigned)l2 | ((unsigned)l3 << 16));
    }
  };

  const f32x4 zero4 = {0.f, 0.f, 0.f, 0.f};
  auto computeS = [&](f32x4* acc) {
#pragma unroll
    for (int t = 0; t < 4; ++t) {
      acc[t] = zero4;
      int row = t * 16 + c;
      int rbase = row * 256;
      int sw = (row & 7) << 4;
#pragma unroll
      for (int c2 = 0; c2 < 4; ++c2) {
        int off = rbase + ((c2 * 64 + g * 16) ^ sw);
        bf16x8 kh_ = *(const bf16x8*)((const char*)khi + off);
        bf16x8 kl_ = *(const bf16x8*)((const char*)klo + off);
        acc[t] = __builtin_amdgcn_mfma_f32_16x16x32_bf16(qhi[c2], kh_, acc[t], 0, 0, 0);
        acc[t] = __builtin_amdgcn_mfma_f32_16x16x32_bf16(qhi[c2], kl_, acc[t], 0, 0, 0);
        acc[t] = __builtin_amdgcn_mfma_f32_16x16x32_bf16(qlo[c2], kh_, acc[t], 0, 0, 0);
      }
    }
  };

  float rsum[4] = {0.f, 0.f, 0.f, 0.f};
  for (int kb = 0; kb <= qb; ++kb) {
    __syncthreads();
    stageK(kb);
    __syncthreads();
    f32x4 acc[4];
    computeS(acc);
#pragma unroll
    for (int r2 = 0; r2 < 4; ++r2) {
      int qg = q0 + w * 16 + g * 4 + r2;
      float s0 = 0.f;
#pragma unroll
      for (int t = 0; t < 4; ++t) {
        int kg = kb * KB_ + t * 16 + c;
        float e = (kg <= qg) ? __expf(acc[t][r2]) : 0.f;
        s0 += e;
      }
#pragma unroll
      for (int m = 1; m <= 8; m <<= 1) s0 += __shfl_xor(s0, m, 64);
      rsum[r2] += s0;
    }
  }
  float invl[4];
#pragma unroll
  for (int r2 = 0; r2 < 4; ++r2) invl[r2] = 1.0f / rsum[r2];

  f32x4 oacc[8];
#pragma unroll
  for (int dt = 0; dt < 8; ++dt) oacc[dt] = zero4;

  for (int kb = 0; kb <= qb; ++kb) {
    __syncthreads();
    stageK(kb);
#pragma unroll
    for (int rr = 0; rr < 8; ++rr) {
      int d0 = 4 * (w + 4 * rr);
      const float* src = Vb + (size_t)(kb * KB_ + lane) * D_ + d0;
      float4 f = *(const float4*)src;
      float xs[4] = {f.x, f.y, f.z, f.w};
#pragma unroll
      for (int i = 0; i < 4; ++i) {
        int d = d0 + i;
        int off = d * 128 + ((lane * 2) ^ ((d & 7) << 4));
        *(unsigned short*)((char*)vts + off) = f2bf(xs[i]);
      }
    }
    __syncthreads();

    f32x4 acc[4];
    computeS(acc);

#pragma unroll
    for (int r2 = 0; r2 < 4; ++r2) {
      int qrow = g * 4 + r2;
      int qg = q0 + w * 16 + qrow;
#pragma unroll
      for (int t = 0; t < 4; ++t) {
        int kc = t * 16 + c;
        int kg = kb * KB_ + kc;
        float p = (kg <= qg) ? __expf(acc[t][r2]) * invl[r2] : 0.f;
        attnb[(size_t)qg * S_ + kg] = p;
        int off = qrow * 128 + ((kc * 2) ^ ((qrow & 7) << 4));
        *(unsigned short*)((char*)pls[w] + off) = f2bf(p);
      }
    }
    __syncthreads();

    bf16x8 pa[2];
#pragma unroll
    for (int ks = 0; ks < 2; ++ks) {
      int off = c * 128 + ((ks * 64 + g * 16) ^ ((c & 7) << 4));
      pa[ks] = *(const bf16x8*)((const char*)pls[w] + off);
    }
#pragma unroll
    for (int dt = 0; dt < 8; ++dt) {
      int d = dt * 16 + c;
      int rbase = d * 128;
      int sw = (d & 7) << 4;
#pragma unroll
      for (int ks = 0; ks < 2; ++ks) {
        int off = rbase + ((ks * 64 + g * 16) ^ sw);
        bf16x8 vf = *(const bf16x8*)((const char*)vts + off);
        oacc[dt] = __builtin_amdgcn_mfma_f32_16x16x32_bf16(pa[ks], vf, oacc[dt], 0, 0, 0);
      }
    }
  }

#pragma unroll
  for (int dt = 0; dt < 8; ++dt) {
#pragma unroll
    for (int r2 = 0; r2 < 4; ++r2) {
      int qg = q0 + w * 16 + g * 4 + r2;
      int d = dt * 16 + c;
      float qv = Qb[(size_t)qg * D_ + d];
      outb[(size_t)qg * D_ + d] = oacc[dt][r2] * qv;
    }
  }
}

extern "C" void kernel_launch(void* const* d_in, const int* in_sizes, int n_in,
                              void* d_out, int out_size, void* d_ws, size_t ws_size,
                              hipStream_t stream) {
  const float* q = (const float*)d_in[0];
  const float* k = (const float*)d_in[1];
  const float* v = (const float*)d_in[2];
  float* out  = (float*)d_out;
  float* attn = out + (size_t)BH_ * S_ * D_;

  const size_t nKV = (size_t)BH_ * S_ * D_;             // 4,194,304 elems
  const size_t need = nKV * 2 * 3 + (size_t)BH_ * S_ * 4;  // Khi+Klo+Vt + rsum

  if (ws_size >= need) {
    ushort_t* Khi = (ushort_t*)d_ws;
    ushort_t* Klo = Khi + nKV;
    ushort_t* Vt  = Klo + nKV;
    float* rsumW  = (float*)(Vt + nKV);

    convK<<<dim3((unsigned)(nKV / 8 / 256)), dim3(256), 0, stream>>>(k, Khi, Klo);
    transV<<<dim3(S_ / 64, BH_), dim3(256), 0, stream>>>(v, Vt);
    sdpa_main<<<dim3(16, BH_), dim3(256), 0, stream>>>(q, Khi, Klo, Vt, out, attn, rsumW);
    norm_attn<<<dim3(S_ / 2, BH_), dim3(256), 0, stream>>>(attn, rsumW);
  } else {
    sdpa_fallback<<<dim3(S_ / QB_, BH_), dim3(256), 0, stream>>>(q, k, v, out, attn);
  }
}